// Round 15
// baseline (534.001 us; speedup 1.0000x reference)
//
#include <hip/hip_runtime.h>

typedef __attribute__((ext_vector_type(4))) float f32x4;
typedef __attribute__((ext_vector_type(2))) float f32x2;
typedef __attribute__((ext_vector_type(8))) short short8;
typedef __attribute__((ext_vector_type(8))) __bf16 bf16x8;
typedef __attribute__((ext_vector_type(4))) unsigned short us4;

__device__ __forceinline__ unsigned short f2bf(float f) {
  unsigned u = __builtin_bit_cast(unsigned, f);
  u = (u + 0x7FFFu + ((u >> 16) & 1u)) >> 16;
  return (unsigned short)u;
}

__device__ __forceinline__ f32x4 mfma16(short8 a, short8 b, f32x4 c) {
  return __builtin_amdgcn_mfma_f32_16x16x32_bf16(
      __builtin_bit_cast(bf16x8, a), __builtin_bit_cast(bf16x8, b), c, 0, 0, 0);
}

// async global->LDS, 16B per lane. LDS dest is wave-uniform base; HW adds lane*16.
__device__ __forceinline__ void gload16(const unsigned short* g, unsigned short* l) {
  __builtin_amdgcn_global_load_lds((const __attribute__((address_space(1))) void*)g,
                                   (__attribute__((address_space(3))) void*)l, 16, 0, 0);
}

// raw LDS read the compiler can't alias-track.  Caller supplies lgkmcnt waits.
__device__ __forceinline__ short8 ds_read128(unsigned off) {
  short8 r;
  asm volatile("ds_read_b128 %0, %1" : "=v"(r) : "v"(off));
  return r;
}

__device__ __forceinline__ f32x2 lo2(f32x4 v) { return __builtin_shufflevector(v, v, 0, 1); }
__device__ __forceinline__ f32x2 hi2(f32x4 v) { return __builtin_shufflevector(v, v, 2, 3); }

// ---------------------------------------------------------------------------
// FRONT mega-kernel: blocks 0..127 = Cayley; 128..2047 = fp32->bf16 convert;
// 2048..2063 = zero VbfT.
// ---------------------------------------------------------------------------
struct CayleyPtrs {
  const float* P[8];
  float* Q[8];
};

__launch_bounds__(256)
__global__ void front_kernel(CayleyPtrs ptrs, const float* __restrict__ hidden,
                             unsigned short* __restrict__ Xbf,
                             unsigned short* __restrict__ VbfT) {
  __shared__ float M[80 * 80];
  __shared__ float R[80 * 80];
  __shared__ float fcol[80];
  int bid = blockIdx.x, tid = threadIdx.x;

  if (bid < 128) {
    int t = bid >> 4, g = bid & 15;
    int n = (t < 6) ? 80 : 48;
    const float* Pg = ptrs.P[t] + (size_t)g * n * n;
    float* Qg = ptrs.Q[t] + (size_t)g * n * n;

    for (int idx = tid; idx < n * n; idx += 256) {
      int i = idx / n, j = idx - i * n;
      float a = Pg[i * n + j] - Pg[j * n + i];
      float id = (i == j) ? 1.0f : 0.0f;
      M[idx] = id - a;
      R[idx] = id + a;
    }
    __syncthreads();

    int nch = n >> 2;
    int tot = n * nch;
    for (int k = 0; k < n; ++k) {
      if (tid < n) {
        float inv = 1.0f / M[k * n + k];
        fcol[tid] = (tid == k) ? 0.0f : M[tid * n + k] * inv;
      }
      __syncthreads();
      for (int idx = tid; idx < tot; idx += 256) {
        int i = idx / nch, c = idx - i * nch;
        float f = fcol[i];
        ((f32x4*)&R[i * n])[c] = ((f32x4*)&R[i * n])[c] - f * ((const f32x4*)&R[k * n])[c];
      }
      int c0 = k >> 2, mw = nch - c0, totM = n * mw;
      for (int idx = tid; idx < totM; idx += 256) {
        int i = idx / mw, c = c0 + idx - i * mw;
        float f = fcol[i];
        ((f32x4*)&M[i * n])[c] = ((f32x4*)&M[i * n])[c] - f * ((const f32x4*)&M[k * n])[c];
      }
      __syncthreads();
    }
    for (int idx = tid; idx < n * n; idx += 256) {
      int i = idx / n;
      Qg[idx] = R[idx] / M[i * n + i];
    }
  } else if (bid < 2048) {
    long long nEl = 32768LL * 1280;
    long long i = ((long long)(bid - 128) * 256 + tid) * 4;
    long long stride = 1920LL * 256 * 4;
    for (; i < nEl; i += stride) {
      f32x4 v = *(const f32x4*)(hidden + i);
      us4 o;
      o[0] = f2bf(v[0]); o[1] = f2bf(v[1]); o[2] = f2bf(v[2]); o[3] = f2bf(v[3]);
      *(us4*)(Xbf + i) = o;
    }
  } else {
    long long nCh = 1280LL * 656 / 8;
    long long i = (long long)(bid - 2048) * 256 + tid;
    short8 zz = {0, 0, 0, 0, 0, 0, 0, 0};
    for (; i < nCh; i += 16LL * 256) *((short8*)VbfT + i) = zz;
  }
}

// ---------------------------------------------------------------------------
// Fused effective weights: grid (16,16,4). 4x4 reg blocking, k-chunk rotation
// (conflict fix), f32x2 PACKED accumulation -> v_pk_fma_f32 (2x fp32 rate).
// ---------------------------------------------------------------------------
struct BuildArgs {
  const float* Qin[4];
  const float* W[4];
  const float* Qout[4];
  const float* scale[4];
  unsigned short* WeffT[4];
  float extra[4];
  int b[4];
  int Kin[4];
};

#define BS 84  // LDS row stride in floats

__launch_bounds__(256)
__global__ void build_all(BuildArgs A) {
  __shared__ float Qs[80 * BS];
  __shared__ float Ws[80 * BS];
  __shared__ float T1[80 * BS];
  int z = blockIdx.z;
  int gi = blockIdx.x, go = blockIdx.y, tid = threadIdx.x;
  int b = A.b[z], Kin = A.Kin[z];
  float extra = A.extra[z];
  const float* Qin = A.Qin[z];
  const float* W = A.W[z];
  const float* Qout = A.Qout[z];
  const float* scale = A.scale[z];
  unsigned short* WeffT = A.WeffT[z];

  for (int idx = tid; idx < b * b; idx += 256) {
    int i = idx / b, j = idx - i * b;
    Qs[i * BS + j] = Qin[(size_t)gi * b * b + idx];
  }
  for (int idx = tid; idx < 80 * b; idx += 256) {
    int m = idx / b, j = idx - m * b;
    Ws[m * BS + j] = W[(size_t)(go * 80 + m) * Kin + gi * b + j];
  }
  __syncthreads();

  int itiles = b >> 2;
  int jch = b >> 2;
  int NT = itiles * 20;
  // product 1: T1[i][m] = sum_j Qs[i][j] * Ws[m][j]   (k-chunks rotated by tm)
  for (int t = tid; t < NT; t += 256) {
    int ti = t / 20, tm = t - ti * 20;
    int tmr = (tm >= jch) ? tm - jch : tm;
    f32x2 acc[4][4] = {};
    for (int jc0 = 0; jc0 < jch; ++jc0) {
      int jc = jc0 + tmr; if (jc >= jch) jc -= jch;
      f32x4 qa[4], wb[4];
#pragma unroll
      for (int p = 0; p < 4; ++p) qa[p] = *(const f32x4*)&Qs[(4 * ti + p) * BS + jc * 4];
#pragma unroll
      for (int p = 0; p < 4; ++p) wb[p] = *(const f32x4*)&Ws[(4 * tm + p) * BS + jc * 4];
#pragma unroll
      for (int p = 0; p < 4; ++p)
#pragma unroll
        for (int q = 0; q < 4; ++q)
          acc[p][q] += lo2(qa[p]) * lo2(wb[q]) + hi2(qa[p]) * hi2(wb[q]);
    }
#pragma unroll
    for (int p = 0; p < 4; ++p)
#pragma unroll
      for (int q = 0; q < 4; ++q)
        T1[(4 * ti + p) * BS + 4 * tm + q] = acc[p][q][0] + acc[p][q][1];
  }
  __syncthreads();
  for (int idx = tid; idx < 6400; idx += 256) {
    int m = idx / 80, n = idx - m * 80;
    Qs[n * BS + m] = Qout[(size_t)go * 6400 + idx];
  }
  __syncthreads();
  // product 2: Out[i][n] = sum_m T1[i][m] * QoT[n][m]  (k-chunks rotated by tn)
  for (int t = tid; t < NT; t += 256) {
    int ti = t / 20, tn = t - ti * 20;
    f32x2 acc[4][4] = {};
    for (int mc0 = 0; mc0 < 20; ++mc0) {
      int mc = mc0 + tn; if (mc >= 20) mc -= 20;
      f32x4 ta[4], qb[4];
#pragma unroll
      for (int p = 0; p < 4; ++p) ta[p] = *(const f32x4*)&T1[(4 * ti + p) * BS + mc * 4];
#pragma unroll
      for (int p = 0; p < 4; ++p) qb[p] = *(const f32x4*)&Qs[(4 * tn + p) * BS + mc * 4];
#pragma unroll
      for (int p = 0; p < 4; ++p)
#pragma unroll
        for (int q = 0; q < 4; ++q)
          acc[p][q] += lo2(ta[p]) * lo2(qb[q]) + hi2(ta[p]) * hi2(qb[q]);
    }
#pragma unroll
    for (int q = 0; q < 4; ++q) {
      int col = go * 80 + 4 * tn + q;
      float sc = scale[col] * extra;
#pragma unroll
      for (int p = 0; p < 4; ++p)
        WeffT[(size_t)col * Kin + gi * b + 4 * ti + p] =
            f2bf((acc[p][q][0] + acc[p][q][1]) * sc);
    }
  }
}

// ---------------------------------------------------------------------------
// 128x128 GEMM body v2: BK=32, 32KB LDS (As0|As1|Bs0|Bs1, 8KB each) ->
// 4-5 blocks/CU (vs 2 at BK=64).  Counted-vmcnt pipeline, raw barriers,
// asm ds_read.  Conflict-free BK=32 XOR swizzle (both-sides):
//   LDS[row][slot] holds global chunk slot ^ ((row>>1)&3)
//   staged via source chunk (l&3)^((l>>3)&3) (linear gload dest),
//   read at slot hi ^ ((lo>>1)&3)  -> 16 lanes hit 8 distinct bank-groups
//   (2-way = free, m136).  4 gloads/wave/tile -> vmcnt(4) steady-state.
// ---------------------------------------------------------------------------
template <bool CF32, bool BIAS>
__device__ __forceinline__ void gemm128_body(unsigned short* sh,
                                             const unsigned short* A,
                                             const unsigned short* Bt,
                                             void* Cp, const float* bias,
                                             int M, int N, int K, int nid) {
  unsigned short* As0 = sh;            // 128 x 32 shorts = 8KB
  unsigned short* As1 = sh + 4096;
  unsigned short* Bs0 = sh + 8192;
  unsigned short* Bs1 = sh + 12288;
  int nbn = N >> 7;
  int bm = nid / nbn, bn = nid - bm * nbn;
  int row0 = bm << 7, col0 = bn << 7;

  int tid = threadIdx.x;
  int w = tid >> 6, l = tid & 63, lo = l & 15, hi = l >> 4;
  int wm = w >> 1, wn = w & 1;
  int rsw2 = (lo >> 1) & 3;
  int slot = (hi ^ rsw2) << 4;         // byte offset of this lane's 16B slot

  // staging: wave w covers rows [w*32,+32); 2 gloads each of 16 rows.
  int sr = l >> 2;                     // row within a gload
  int chunk = (l & 3) ^ ((l >> 3) & 3);
  const unsigned short* Ag = A + (size_t)(row0 + w * 32 + sr) * K + chunk * 8;
  const unsigned short* Bg = Bt + (size_t)(col0 + w * 32 + sr) * K + chunk * 8;

  unsigned a0b = (unsigned)(size_t)As0, a1b = (unsigned)(size_t)As1;
  unsigned b0b = (unsigned)(size_t)Bs0, b1b = (unsigned)(size_t)Bs1;

  int NT = K >> 5;

  f32x4 z = {0.0f, 0.0f, 0.0f, 0.0f};
  f32x4 acc[4][4];
#pragma unroll
  for (int m = 0; m < 4; ++m)
#pragma unroll
    for (int n = 0; n < 4; ++n) acc[m][n] = z;

  auto stage = [&](int t, unsigned short* la0, unsigned short* lb0) {
    const unsigned short* ag = Ag + t * 32;
    const unsigned short* bg = Bg + t * 32;
    unsigned short* la = la0 + w * 1024;   // 32 rows x 32 shorts
    unsigned short* lb = lb0 + w * 1024;
    gload16(ag, la);
    gload16(ag + (size_t)16 * K, la + 512);
    gload16(bg, lb);
    gload16(bg + (size_t)16 * K, lb + 512);
  };

  stage(0, As0, Bs0);
  stage(1, As1, Bs1);

  for (int t = 0; t < NT; ++t) {
    unsigned cAb = (t & 1) ? a1b : a0b;
    unsigned cBb = (t & 1) ? b1b : b0b;
    if (t == NT - 1) asm volatile("s_waitcnt vmcnt(0)" ::: "memory");
    else             asm volatile("s_waitcnt vmcnt(4)" ::: "memory");
    __builtin_amdgcn_s_barrier();
    __builtin_amdgcn_sched_barrier(0);

    short8 bf[4], af[4];
#pragma unroll
    for (int ni = 0; ni < 4; ++ni)
      bf[ni] = ds_read128(cBb + (unsigned)((wn * 64 + ni * 16 + lo) * 64 + slot));
#pragma unroll
    for (int mi = 0; mi < 4; ++mi)
      af[mi] = ds_read128(cAb + (unsigned)((wm * 64 + mi * 16 + lo) * 64 + slot));

    asm volatile("s_waitcnt lgkmcnt(0)" ::: "memory");
    __builtin_amdgcn_sched_barrier(0);   // rule #18
    __builtin_amdgcn_s_setprio(1);
#pragma unroll
    for (int mi = 0; mi < 4; ++mi)
#pragma unroll
      for (int ni = 0; ni < 4; ++ni)
        acc[mi][ni] = mfma16(af[mi], bf[ni], acc[mi][ni]);
    __builtin_amdgcn_s_setprio(0);

    __builtin_amdgcn_sched_barrier(0);
    __builtin_amdgcn_s_barrier();        // all waves done reading this buffer
    if (t + 2 < NT) {
      if (t & 1) stage(t + 2, As1, Bs1);
      else       stage(t + 2, As0, Bs0);
    }
  }

#pragma unroll
  for (int m = 0; m < 4; ++m)
#pragma unroll
    for (int n = 0; n < 4; ++n) {
      int col = col0 + wn * 64 + n * 16 + lo;
#pragma unroll
      for (int j = 0; j < 4; ++j) {
        int row = row0 + wm * 64 + m * 16 + hi * 4 + j;
        float v = acc[m][n][j];
        if (BIAS) v += bias[col];
        if (CF32) ((float*)Cp)[(size_t)row * N + col] = v;
        else ((unsigned short*)Cp)[(size_t)row * N + col] = f2bf(v);
      }
    }
}

template <bool CF32, bool BIAS>
__launch_bounds__(256, 4)
__global__ void gemm128(const unsigned short* __restrict__ A,
                        const unsigned short* __restrict__ Bt,
                        void* __restrict__ Cp, const float* __restrict__ bias,
                        int M, int N, int K) {
  __shared__ alignas(128) unsigned short sh[16384];  // 32KB
  int per = gridDim.x >> 3;
  int nid = (blockIdx.x & 7) * per + (blockIdx.x >> 3);
  gemm128_body<CF32, BIAS>(sh, A, Bt, Cp, bias, M, N, K, nid);
}

// ---------------------------------------------------------------------------
// K/V projection body (M=616 guarded, fp32 A). z=0: K normal; z=1: V transposed.
// Uses 20KB of sh (fits the 32KB union).
// ---------------------------------------------------------------------------
__device__ __forceinline__ void kv_body(unsigned short* sh,
                                        const float* __restrict__ enc,
                                        const unsigned short* __restrict__ Bt,
                                        unsigned short* __restrict__ Kbf,
                                        unsigned short* __restrict__ VbfT,
                                        int bn, int bm, int z) {
  const int M = 616, N = 1280, K = 768;
  unsigned short* As = sh;            // [128][40]
  unsigned short* Bs = sh + 5120;     // [128][40]
  int tid = threadIdx.x;
  int l = tid & 63, wid = tid >> 6, lo = l & 15, hi = l >> 4;
  int wm = wid >> 1, wn = wid & 1;
  f32x4 zr = {0.0f, 0.0f, 0.0f, 0.0f};
  f32x4 acc[4][4];
#pragma unroll
  for (int m = 0; m < 4; ++m)
#pragma unroll
    for (int n = 0; n < 4; ++n) acc[m][n] = zr;
  int row0 = bm * 128;
  int ar = tid >> 2, acg = tid & 3;
  int bnr = tid >> 1, bhf = tid & 1;

  for (int k0 = 0; k0 < K; k0 += 32) {
    __syncthreads();
#pragma unroll
    for (int rr = 0; rr < 2; ++rr) {
      int row = ar + rr * 64;
      int grow = row0 + row;
      short8 v = {0, 0, 0, 0, 0, 0, 0, 0};
      if (grow < M) {
        const float* ap = enc + (size_t)grow * K + k0 + acg * 8;
        f32x4 v0 = *(const f32x4*)ap;
        f32x4 v1 = *(const f32x4*)(ap + 4);
        v[0] = (short)f2bf(v0[0]); v[1] = (short)f2bf(v0[1]);
        v[2] = (short)f2bf(v0[2]); v[3] = (short)f2bf(v0[3]);
        v[4] = (short)f2bf(v1[0]); v[5] = (short)f2bf(v1[1]);
        v[6] = (short)f2bf(v1[2]); v[7] = (short)f2bf(v1[3]);
      }
      *(short8*)&As[row * 40 + acg * 8] = v;
    }
    {
      const unsigned short* bp = Bt + (size_t)(bn * 128 + bnr) * K + k0 + bhf * 16;
      *(short8*)&Bs[bnr * 40 + bhf * 16] = *(const short8*)bp;
      *(short8*)&Bs[bnr * 40 + bhf * 16 + 8] = *(const short8*)(bp + 8);
    }
    __syncthreads();
    short8 af[4], bf[4];
#pragma unroll
    for (int m = 0; m < 4; ++m) af[m] = *(const short8*)&As[(wm * 64 + m * 16 + lo) * 40 + hi * 8];
#pragma unroll
    for (int n = 0; n < 4; ++n) bf[n] = *(const short8*)&Bs[(wn * 64 + n * 16 + lo) * 40 + hi * 8];
#pragma unroll
    for (int m = 0; m < 4; ++m)
#pragma unroll
      for (int n = 0; n < 4; ++n) acc[m][n] = mfma16(af[m], bf[n], acc[m][n]);
  }

#pragma unroll
  for (int m = 0; m < 4; ++m)
#pragma unroll
    for (int n = 0; n < 4; ++n) {
      int col = bn * 128 + wn * 64 + n * 16 + lo;
#pragma unroll
      for (int j = 0; j < 4; ++j) {
        int row = row0 + wm * 64 + m * 16 + hi * 4 + j;
        if (row < M) {
          unsigned short v = f2bf(acc[m][n][j]);
          if (z) {
            int bb = row / 77, tt = row - bb * 77;
            VbfT[(size_t)col * 656 + bb * 80 + tt] = v;
          } else {
            Kbf[(size_t)row * N + col] = v;
          }
        }
      }
    }
}

// ---------------------------------------------------------------------------
// Fused launch: blocks 0..99 = K/V projections (first, overlap gemm wave 1);
// 100..2659 = Q-GEMM.
// ---------------------------------------------------------------------------
__launch_bounds__(256, 4)
__global__ void gemm_qkv(const unsigned short* __restrict__ Xbf,
                         const unsigned short* __restrict__ WqT,
                         unsigned short* __restrict__ Qbf,
                         const float* __restrict__ enc,
                         const unsigned short* __restrict__ WkT,
                         const unsigned short* __restrict__ WvT,
                         unsigned short* __restrict__ Kbf,
                         unsigned short* __restrict__ VbfT) {
  __shared__ alignas(128) unsigned short sh[16384];
  int bid = blockIdx.x;
  if (bid < 100) {
    int z = bid / 50, r = bid - z * 50;
    int bm = r / 10, bn = r - bm * 10;
    kv_body(sh, enc, z ? WvT : WkT, Kbf, VbfT, bn, bm, z);
  } else {
    int b2 = bid - 100;
    int nid = (b2 & 7) * 320 + (b2 >> 3);   // bijective XCD swizzle over 2560
    gemm128_body<false, false>(sh, Xbf, WqT, Qbf, nullptr, 32768, 1280, 1280, nid);
  }
}

// ---------------------------------------------------------------------------
// Attention: Sk=77 single tile.  Q/K from global; V from global V^T [1280][656].
// ---------------------------------------------------------------------------
#define QB 64
__launch_bounds__(256)
__global__ void attn_kernel(const unsigned short* __restrict__ Q,
                            const unsigned short* __restrict__ Kp,
                            const unsigned short* __restrict__ VpT,
                            unsigned short* __restrict__ O) {
  __shared__ alignas(16) unsigned short Ps[QB][104];
  int tile = blockIdx.x, bh = blockIdx.y;
  int b = bh >> 3, h = bh & 7;
  int tid = threadIdx.x;

  for (int cid = tid; cid < QB * 16; cid += 256) {
    int r = cid / 16, c = 80 + (cid & 15);
    Ps[r][c] = 0;
  }

  int l = tid & 63, wid = tid >> 6, lo = l & 15, hi = l >> 4;

  const unsigned short* qrow =
      Q + (size_t)(b * 4096 + tile * QB + wid * 16 + lo) * 1280 + h * 160;
  short8 a[5];
#pragma unroll
  for (int kt = 0; kt < 5; ++kt) a[kt] = *(const short8*)&qrow[kt * 32 + hi * 8];

  const unsigned short* Kb = Kp + (size_t)(b * 77) * 1280 + h * 160;
  f32x4 z = {0.0f, 0.0f, 0.0f, 0.0f};
  f32x4 sc[5];
#pragma unroll
  for (int n = 0; n < 5; ++n) sc[n] = z;
#pragma unroll
  for (int n = 0; n < 5; ++n) {
    const unsigned short* krow = Kb + (size_t)(n * 16 + lo) * 1280;
#pragma unroll
    for (int kt = 0; kt < 5; ++kt) {
      short8 bb = *(const short8*)&krow[kt * 32 + hi * 8];
      sc[n] = mfma16(a[kt], bb, sc[n]);
    }
  }
  if (lo >= 13) { sc[4][0] = -1e30f; sc[4][1] = -1e30f; sc[4][2] = -1e30f; sc[4][3] = -1e30f; }

  float pinv[4];
#pragma unroll
  for (int j = 0; j < 4; ++j) {
    float mx = sc[0][j];
#pragma unroll
    for (int n = 1; n < 5; ++n) mx = fmaxf(mx, sc[n][j]);
#pragma unroll
    for (int msk = 1; msk < 16; msk <<= 1) mx = fmaxf(mx, __shfl_xor(mx, msk, 64));
    float s = 0.0f;
#pragma unroll
    for (int n = 0; n < 5; ++n) {
      float p = __expf(sc[n][j] - mx);
      sc[n][j] = p;
      s += p;
    }
#pragma unroll
    for (int msk = 1; msk < 16; msk <<= 1) s += __shfl_xor(s, msk, 64);
    pinv[j] = 1.0f / s;
  }
#pragma unroll
  for (int n = 0; n < 5; ++n)
#pragma unroll
    for (int j = 0; j < 4; ++j)
      Ps[wid * 16 + hi * 4 + j][n * 16 + lo] = f2bf(sc[n][j] * pinv[j]);
  __syncthreads();

  f32x4 o[10];
#pragma unroll
  for (int n = 0; n < 10; ++n) o[n] = z;
#pragma unroll
  for (int kt = 0; kt < 3; ++kt) {
    short8 pa = *(const short8*)&Ps[wid * 16 + lo][kt * 32 + hi * 8];
#pragma unroll
    for (int n = 0; n < 10; ++n) {
      const unsigned short* vrow = VpT + (size_t)(h * 160 + n * 16 + lo) * 656 + b * 80;
      short8 vb = *(const short8*)&vrow[kt * 32 + hi * 8];
      o[n] = mfma16(pa, vb, o[n]);
    }
  }
  unsigned short* Ob = O + (size_t)(b * 4096 + tile * QB + wid * 16 + hi * 4) * 1280 + h * 160;
#pragma unroll
  for (int n = 0; n < 10; ++n)
#pragma unroll
    for (int j = 0; j < 4; ++j)
      Ob[(size_t)j * 1280 + n * 16 + lo] = f2bf(o[n][j]);
}

// ---------------------------------------------------------------------------
extern "C" void kernel_launch(void* const* d_in, const int* in_sizes, int n_in,
                              void* d_out, int out_size, void* d_ws, size_t ws_size,
                              hipStream_t stream) {
  const float* hidden   = (const float*)d_in[0];
  const float* enc      = (const float*)d_in[1];
  const float* Pq_in    = (const float*)d_in[2];
  const float* Pk_in    = (const float*)d_in[3];
  const float* Pv_in    = (const float*)d_in[4];
  const float* Pout_in  = (const float*)d_in[5];
  const float* Pq_out   = (const float*)d_in[6];
  const float* Pk_out   = (const float*)d_in[7];
  const float* Pv_out   = (const float*)d_in[8];
  const float* Pout_out = (const float*)d_in[9];
  const float* Wq       = (const float*)d_in[10];
  const float* Wk       = (const float*)d_in[11];
  const float* Wv       = (const float*)d_in[12];
  const float* Wout     = (const float*)d_in[13];
  const float* bout     = (const float*)d_in[14];
  const float* q_scale  = (const float*)d_in[15];
  const float* k_scale  = (const float*)d_in[16];
  const float* v_scale  = (const float*)d_in[17];
  const float* out_scale= (const float*)d_in[18];

  char* w = (char*)d_ws;
  unsigned short* attnO = (unsigned short*)w; w += 32768LL * 1280 * 2;
  unsigned short* WqT   = (unsigned short*)w; w += 1280LL * 1280 * 2;
  unsigned short* WkT   = (unsigned short*)w; w += 1280LL * 768 * 2;
  unsigned short* WvT   = (unsigned short*)w; w += 1280LL * 768 * 2;
  unsigned short* WoT   = (unsigned short*)w; w += 1280LL * 1280 * 2;
  unsigned short* Kbf   = (unsigned short*)w; w += 616LL * 1280 * 2;
  unsigned short* VbfT  = (unsigned short*)w; w += 1280LL * 656 * 2;
  float* cQq_in   = (float*)w; w += 16LL * 80 * 80 * 4;
  float* cQout_in = (float*)w; w += 16LL * 80 * 80 * 4;
  float* cQq_out  = (float*)w; w += 16LL * 80 * 80 * 4;
  float* cQk_out  = (float*)w; w += 16LL * 80 * 80 * 4;
  float* cQv_out  = (float*)w; w += 16LL * 80 * 80 * 4;
  float* cQout_out= (float*)w; w += 16LL * 80 * 80 * 4;
  float* cQk_in   = (float*)w; w += 16LL * 48 * 48 * 4;
  float* cQv_in   = (float*)w; w += 16LL * 48 * 48 * 4;

  unsigned short* Xbf = (unsigned short*)d_out;
  unsigned short* Qbf = Xbf + 32768LL * 1280;

  CayleyPtrs cp;
  cp.P[0] = Pq_in;    cp.Q[0] = cQq_in;
  cp.P[1] = Pout_in;  cp.Q[1] = cQout_in;
  cp.P[2] = Pq_out;   cp.Q[2] = cQq_out;
  cp.P[3] = Pk_out;   cp.Q[3] = cQk_out;
  cp.P[4] = Pv_out;   cp.Q[4] = cQv_out;
  cp.P[5] = Pout_out; cp.Q[5] = cQout_out;
  cp.P[6] = Pk_in;    cp.Q[6] = cQk_in;
  cp.P[7] = Pv_in;    cp.Q[7] = cQv_in;

  // 1. front: cayley (128) + f32->bf16 convert (1920) + VbfT zero (16)
  front_kernel<<<2064, 256, 0, stream>>>(cp, hidden, Xbf, VbfT);

  // 2. effective weights
  const float ATTN_SCALE = 0.07905694150420949f;  // 160^-0.5
  BuildArgs ba;
  ba.Qin[0] = cQq_in;   ba.W[0] = Wq;   ba.Qout[0] = cQq_out;   ba.scale[0] = q_scale;
  ba.WeffT[0] = WqT;    ba.extra[0] = ATTN_SCALE; ba.b[0] = 80; ba.Kin[0] = 1280;
  ba.Qin[1] = cQk_in;   ba.W[1] = Wk;   ba.Qout[1] = cQk_out;   ba.scale[1] = k_scale;
  ba.WeffT[1] = WkT;    ba.extra[1] = 1.0f;       ba.b[1] = 48; ba.Kin[1] = 768;
  ba.Qin[2] = cQv_in;   ba.W[2] = Wv;   ba.Qout[2] = cQv_out;   ba.scale[2] = v_scale;
  ba.WeffT[2] = WvT;    ba.extra[2] = 1.0f;       ba.b[2] = 48; ba.Kin[2] = 768;
  ba.Qin[3] = cQout_in; ba.W[3] = Wout; ba.Qout[3] = cQout_out; ba.scale[3] = out_scale;
  ba.WeffT[3] = WoT;    ba.extra[3] = 1.0f;       ba.b[3] = 80; ba.Kin[3] = 1280;
  build_all<<<dim3(16, 16, 4), 256, 0, stream>>>(ba);

  // 3. K/V projections (first) + Q projection in one launch
  gemm_qkv<<<2660, 256, 0, stream>>>(Xbf, WqT, Qbf, enc, WkT, WvT, Kbf, VbfT);
  // 4. attention
  attn_kernel<<<dim3(64, 64), 256, 0, stream>>>(Qbf, Kbf, VbfT, attnO);
  // 5. output projection + bias
  gemm128<true, true><<<2560, 256, 0, stream>>>(attnO, WoT, d_out, bout, 32768, 1280, 1280);
}

// Round 16
// 506.862 us; speedup vs baseline: 1.0535x; 1.0535x over previous
//
#include <hip/hip_runtime.h>

typedef __attribute__((ext_vector_type(4))) float f32x4;
typedef __attribute__((ext_vector_type(2))) float f32x2;
typedef __attribute__((ext_vector_type(8))) short short8;
typedef __attribute__((ext_vector_type(8))) __bf16 bf16x8;
typedef __attribute__((ext_vector_type(4))) unsigned short us4;

__device__ __forceinline__ unsigned short f2bf(float f) {
  unsigned u = __builtin_bit_cast(unsigned, f);
  u = (u + 0x7FFFu + ((u >> 16) & 1u)) >> 16;
  return (unsigned short)u;
}

__device__ __forceinline__ f32x4 mfma16(short8 a, short8 b, f32x4 c) {
  return __builtin_amdgcn_mfma_f32_16x16x32_bf16(
      __builtin_bit_cast(bf16x8, a), __builtin_bit_cast(bf16x8, b), c, 0, 0, 0);
}

// async global->LDS, 16B per lane. LDS dest is wave-uniform base; HW adds lane*16.
__device__ __forceinline__ void gload16(const unsigned short* g, unsigned short* l) {
  __builtin_amdgcn_global_load_lds((const __attribute__((address_space(1))) void*)g,
                                   (__attribute__((address_space(3))) void*)l, 16, 0, 0);
}

// raw LDS read the compiler can't alias-track.  Caller supplies lgkmcnt waits.
__device__ __forceinline__ short8 ds_read128(unsigned off) {
  short8 r;
  asm volatile("ds_read_b128 %0, %1" : "=v"(r) : "v"(off));
  return r;
}

__device__ __forceinline__ f32x2 lo2(f32x4 v) { return __builtin_shufflevector(v, v, 0, 1); }
__device__ __forceinline__ f32x2 hi2(f32x4 v) { return __builtin_shufflevector(v, v, 2, 3); }

// ---------------------------------------------------------------------------
// FRONT mega-kernel: blocks 0..127 = Cayley; 128..2047 = fp32->bf16 convert;
// 2048..2063 = zero VbfT.
// ---------------------------------------------------------------------------
struct CayleyPtrs {
  const float* P[8];
  float* Q[8];
};

__launch_bounds__(256)
__global__ void front_kernel(CayleyPtrs ptrs, const float* __restrict__ hidden,
                             unsigned short* __restrict__ Xbf,
                             unsigned short* __restrict__ VbfT) {
  __shared__ float M[80 * 80];
  __shared__ float R[80 * 80];
  __shared__ float fcol[80];
  int bid = blockIdx.x, tid = threadIdx.x;

  if (bid < 128) {
    int t = bid >> 4, g = bid & 15;
    int n = (t < 6) ? 80 : 48;
    const float* Pg = ptrs.P[t] + (size_t)g * n * n;
    float* Qg = ptrs.Q[t] + (size_t)g * n * n;

    for (int idx = tid; idx < n * n; idx += 256) {
      int i = idx / n, j = idx - i * n;
      float a = Pg[i * n + j] - Pg[j * n + i];
      float id = (i == j) ? 1.0f : 0.0f;
      M[idx] = id - a;
      R[idx] = id + a;
    }
    __syncthreads();

    int nch = n >> 2;
    int tot = n * nch;
    for (int k = 0; k < n; ++k) {
      if (tid < n) {
        float inv = 1.0f / M[k * n + k];
        fcol[tid] = (tid == k) ? 0.0f : M[tid * n + k] * inv;
      }
      __syncthreads();
      for (int idx = tid; idx < tot; idx += 256) {
        int i = idx / nch, c = idx - i * nch;
        float f = fcol[i];
        ((f32x4*)&R[i * n])[c] = ((f32x4*)&R[i * n])[c] - f * ((const f32x4*)&R[k * n])[c];
      }
      int c0 = k >> 2, mw = nch - c0, totM = n * mw;
      for (int idx = tid; idx < totM; idx += 256) {
        int i = idx / mw, c = c0 + idx - i * mw;
        float f = fcol[i];
        ((f32x4*)&M[i * n])[c] = ((f32x4*)&M[i * n])[c] - f * ((const f32x4*)&M[k * n])[c];
      }
      __syncthreads();
    }
    for (int idx = tid; idx < n * n; idx += 256) {
      int i = idx / n;
      Qg[idx] = R[idx] / M[i * n + i];
    }
  } else if (bid < 2048) {
    long long nEl = 32768LL * 1280;
    long long i = ((long long)(bid - 128) * 256 + tid) * 4;
    long long stride = 1920LL * 256 * 4;
    for (; i < nEl; i += stride) {
      f32x4 v = *(const f32x4*)(hidden + i);
      us4 o;
      o[0] = f2bf(v[0]); o[1] = f2bf(v[1]); o[2] = f2bf(v[2]); o[3] = f2bf(v[3]);
      *(us4*)(Xbf + i) = o;
    }
  } else {
    long long nCh = 1280LL * 656 / 8;
    long long i = (long long)(bid - 2048) * 256 + tid;
    short8 zz = {0, 0, 0, 0, 0, 0, 0, 0};
    for (; i < nCh; i += 16LL * 256) *((short8*)VbfT + i) = zz;
  }
}

// ---------------------------------------------------------------------------
// Fused effective weights: grid (16,16,4). 4x4 reg blocking, k-chunk rotation
// (conflict fix), f32x2 PACKED accumulation -> v_pk_fma_f32 (2x fp32 rate).
// ---------------------------------------------------------------------------
struct BuildArgs {
  const float* Qin[4];
  const float* W[4];
  const float* Qout[4];
  const float* scale[4];
  unsigned short* WeffT[4];
  float extra[4];
  int b[4];
  int Kin[4];
};

#define BS 84  // LDS row stride in floats

__launch_bounds__(256)
__global__ void build_all(BuildArgs A) {
  __shared__ float Qs[80 * BS];
  __shared__ float Ws[80 * BS];
  __shared__ float T1[80 * BS];
  int z = blockIdx.z;
  int gi = blockIdx.x, go = blockIdx.y, tid = threadIdx.x;
  int b = A.b[z], Kin = A.Kin[z];
  float extra = A.extra[z];
  const float* Qin = A.Qin[z];
  const float* W = A.W[z];
  const float* Qout = A.Qout[z];
  const float* scale = A.scale[z];
  unsigned short* WeffT = A.WeffT[z];

  for (int idx = tid; idx < b * b; idx += 256) {
    int i = idx / b, j = idx - i * b;
    Qs[i * BS + j] = Qin[(size_t)gi * b * b + idx];
  }
  for (int idx = tid; idx < 80 * b; idx += 256) {
    int m = idx / b, j = idx - m * b;
    Ws[m * BS + j] = W[(size_t)(go * 80 + m) * Kin + gi * b + j];
  }
  __syncthreads();

  int itiles = b >> 2;
  int jch = b >> 2;
  int NT = itiles * 20;
  // product 1: T1[i][m] = sum_j Qs[i][j] * Ws[m][j]   (k-chunks rotated by tm)
  for (int t = tid; t < NT; t += 256) {
    int ti = t / 20, tm = t - ti * 20;
    int tmr = (tm >= jch) ? tm - jch : tm;
    f32x2 acc[4][4] = {};
    for (int jc0 = 0; jc0 < jch; ++jc0) {
      int jc = jc0 + tmr; if (jc >= jch) jc -= jch;
      f32x4 qa[4], wb[4];
#pragma unroll
      for (int p = 0; p < 4; ++p) qa[p] = *(const f32x4*)&Qs[(4 * ti + p) * BS + jc * 4];
#pragma unroll
      for (int p = 0; p < 4; ++p) wb[p] = *(const f32x4*)&Ws[(4 * tm + p) * BS + jc * 4];
#pragma unroll
      for (int p = 0; p < 4; ++p)
#pragma unroll
        for (int q = 0; q < 4; ++q)
          acc[p][q] += lo2(qa[p]) * lo2(wb[q]) + hi2(qa[p]) * hi2(wb[q]);
    }
#pragma unroll
    for (int p = 0; p < 4; ++p)
#pragma unroll
      for (int q = 0; q < 4; ++q)
        T1[(4 * ti + p) * BS + 4 * tm + q] = acc[p][q][0] + acc[p][q][1];
  }
  __syncthreads();
  for (int idx = tid; idx < 6400; idx += 256) {
    int m = idx / 80, n = idx - m * 80;
    Qs[n * BS + m] = Qout[(size_t)go * 6400 + idx];
  }
  __syncthreads();
  // product 2: Out[i][n] = sum_m T1[i][m] * QoT[n][m]  (k-chunks rotated by tn)
  for (int t = tid; t < NT; t += 256) {
    int ti = t / 20, tn = t - ti * 20;
    f32x2 acc[4][4] = {};
    for (int mc0 = 0; mc0 < 20; ++mc0) {
      int mc = mc0 + tn; if (mc >= 20) mc -= 20;
      f32x4 ta[4], qb[4];
#pragma unroll
      for (int p = 0; p < 4; ++p) ta[p] = *(const f32x4*)&T1[(4 * ti + p) * BS + mc * 4];
#pragma unroll
      for (int p = 0; p < 4; ++p) qb[p] = *(const f32x4*)&Qs[(4 * tn + p) * BS + mc * 4];
#pragma unroll
      for (int p = 0; p < 4; ++p)
#pragma unroll
        for (int q = 0; q < 4; ++q)
          acc[p][q] += lo2(ta[p]) * lo2(qb[q]) + hi2(ta[p]) * hi2(qb[q]);
    }
#pragma unroll
    for (int q = 0; q < 4; ++q) {
      int col = go * 80 + 4 * tn + q;
      float sc = scale[col] * extra;
#pragma unroll
      for (int p = 0; p < 4; ++p)
        WeffT[(size_t)col * Kin + gi * b + 4 * ti + p] =
            f2bf((acc[p][q][0] + acc[p][q][1]) * sc);
    }
  }
}

// ---------------------------------------------------------------------------
// 128x128 GEMM body (counted-vmcnt pipeline, 2 blocks/CU, XOR-8 swizzle).
// sh = 64KB LDS: As0|As1|Bs0|Bs1 (16KB each).
// ---------------------------------------------------------------------------
template <bool CF32, bool BIAS>
__device__ __forceinline__ void gemm128_body(unsigned short* sh,
                                             const unsigned short* A,
                                             const unsigned short* Bt,
                                             void* Cp, const float* bias,
                                             int M, int N, int K, int nid) {
  unsigned short* As0 = sh;
  unsigned short* As1 = sh + 8192;
  unsigned short* Bs0 = sh + 16384;
  unsigned short* Bs1 = sh + 24576;
  int nbn = N >> 7;
  int bm = nid / nbn, bn = nid - bm * nbn;
  int row0 = bm << 7, col0 = bn << 7;

  int tid = threadIdx.x;
  int w = tid >> 6, l = tid & 63, lo = l & 15, hi = l >> 4;
  int wm = w >> 1, wn = w & 1;
  int rsw = lo & 7;

  int sr8 = l >> 3;
  int chunk = (l & 7) ^ sr8;
  const unsigned short* Ag = A + (size_t)(row0 + w * 32 + sr8) * K + chunk * 8;
  const unsigned short* Bg = Bt + (size_t)(col0 + w * 32 + sr8) * K + chunk * 8;

  unsigned a0b = (unsigned)(size_t)As0, a1b = (unsigned)(size_t)As1;
  unsigned b0b = (unsigned)(size_t)Bs0, b1b = (unsigned)(size_t)Bs1;

  int NT = K >> 6;

  f32x4 z = {0.0f, 0.0f, 0.0f, 0.0f};
  f32x4 acc[4][4];
#pragma unroll
  for (int m = 0; m < 4; ++m)
#pragma unroll
    for (int n = 0; n < 4; ++n) acc[m][n] = z;

  auto stage = [&](int t, unsigned short* la0, unsigned short* lb0) {
    const unsigned short* ag = Ag + t * 64;
    const unsigned short* bg = Bg + t * 64;
    unsigned short* la = la0 + w * 2048;
    unsigned short* lb = lb0 + w * 2048;
#pragma unroll
    for (int i = 0; i < 4; ++i) {
      gload16(ag + (size_t)(i * 8) * K, la + i * 512);
      gload16(bg + (size_t)(i * 8) * K, lb + i * 512);
    }
  };

  stage(0, As0, Bs0);
  stage(1, As1, Bs1);

  for (int t = 0; t < NT; ++t) {
    unsigned cAb = (t & 1) ? a1b : a0b;
    unsigned cBb = (t & 1) ? b1b : b0b;
    if (t == NT - 1) asm volatile("s_waitcnt vmcnt(0)" ::: "memory");
    else             asm volatile("s_waitcnt vmcnt(8)" ::: "memory");
    __builtin_amdgcn_s_barrier();
    __builtin_amdgcn_sched_barrier(0);

    short8 bf[4][2];
#pragma unroll
    for (int ni = 0; ni < 4; ++ni) {
      int col = wn * 64 + ni * 16 + lo;
#pragma unroll
      for (int kk = 0; kk < 2; ++kk)
        bf[ni][kk] = ds_read128(cBb + (unsigned)(col * 128 + (((kk * 4 + hi) ^ rsw) << 4)));
    }
#pragma unroll
    for (int mp = 0; mp < 2; ++mp) {
      short8 af[2][2];
#pragma unroll
      for (int mi = 0; mi < 2; ++mi) {
        int row = wm * 64 + (mp * 2 + mi) * 16 + lo;
#pragma unroll
        for (int kk = 0; kk < 2; ++kk)
          af[mi][kk] = ds_read128(cAb + (unsigned)(row * 128 + (((kk * 4 + hi) ^ rsw) << 4)));
      }
      asm volatile("s_waitcnt lgkmcnt(0)" ::: "memory");
      __builtin_amdgcn_sched_barrier(0);
      __builtin_amdgcn_s_setprio(1);
#pragma unroll
      for (int mi = 0; mi < 2; ++mi)
#pragma unroll
        for (int ni = 0; ni < 4; ++ni) {
          int m = mp * 2 + mi;
          acc[m][ni] = mfma16(af[mi][0], bf[ni][0], acc[m][ni]);
          acc[m][ni] = mfma16(af[mi][1], bf[ni][1], acc[m][ni]);
        }
      __builtin_amdgcn_s_setprio(0);
    }
    __builtin_amdgcn_sched_barrier(0);
    __builtin_amdgcn_s_barrier();
    if (t + 2 < NT) {
      if (t & 1) stage(t + 2, As1, Bs1);
      else       stage(t + 2, As0, Bs0);
    }
  }

#pragma unroll
  for (int m = 0; m < 4; ++m)
#pragma unroll
    for (int n = 0; n < 4; ++n) {
      int col = col0 + wn * 64 + n * 16 + lo;
#pragma unroll
      for (int j = 0; j < 4; ++j) {
        int row = row0 + wm * 64 + m * 16 + hi * 4 + j;
        float v = acc[m][n][j];
        if (BIAS) v += bias[col];
        if (CF32) ((float*)Cp)[(size_t)row * N + col] = v;
        else ((unsigned short*)Cp)[(size_t)row * N + col] = f2bf(v);
      }
    }
}

template <bool CF32, bool BIAS>
__launch_bounds__(256, 2)
__global__ void gemm128(const unsigned short* __restrict__ A,
                        const unsigned short* __restrict__ Bt,
                        void* __restrict__ Cp, const float* __restrict__ bias,
                        int M, int N, int K) {
  __shared__ alignas(128) unsigned short sh[4 * 8192];
  int per = gridDim.x >> 3;
  int nid = (blockIdx.x & 7) * per + (blockIdx.x >> 3);
  gemm128_body<CF32, BIAS>(sh, A, Bt, Cp, bias, M, N, K, nid);
}

// ---------------------------------------------------------------------------
// K/V projection body (M=616 guarded, fp32 A). z=0: K normal; z=1: V transposed.
// ---------------------------------------------------------------------------
__device__ __forceinline__ void kv_body(unsigned short* sh,
                                        const float* __restrict__ enc,
                                        const unsigned short* __restrict__ Bt,
                                        unsigned short* __restrict__ Kbf,
                                        unsigned short* __restrict__ VbfT,
                                        int bn, int bm, int z) {
  const int M = 616, N = 1280, K = 768;
  unsigned short* As = sh;            // [128][40]
  unsigned short* Bs = sh + 5120;     // [128][40]
  int tid = threadIdx.x;
  int l = tid & 63, wid = tid >> 6, lo = l & 15, hi = l >> 4;
  int wm = wid >> 1, wn = wid & 1;
  f32x4 zr = {0.0f, 0.0f, 0.0f, 0.0f};
  f32x4 acc[4][4];
#pragma unroll
  for (int m = 0; m < 4; ++m)
#pragma unroll
    for (int n = 0; n < 4; ++n) acc[m][n] = zr;
  int row0 = bm * 128;
  int ar = tid >> 2, acg = tid & 3;
  int bnr = tid >> 1, bhf = tid & 1;

  for (int k0 = 0; k0 < K; k0 += 32) {
    __syncthreads();
#pragma unroll
    for (int rr = 0; rr < 2; ++rr) {
      int row = ar + rr * 64;
      int grow = row0 + row;
      short8 v = {0, 0, 0, 0, 0, 0, 0, 0};
      if (grow < M) {
        const float* ap = enc + (size_t)grow * K + k0 + acg * 8;
        f32x4 v0 = *(const f32x4*)ap;
        f32x4 v1 = *(const f32x4*)(ap + 4);
        v[0] = (short)f2bf(v0[0]); v[1] = (short)f2bf(v0[1]);
        v[2] = (short)f2bf(v0[2]); v[3] = (short)f2bf(v0[3]);
        v[4] = (short)f2bf(v1[0]); v[5] = (short)f2bf(v1[1]);
        v[6] = (short)f2bf(v1[2]); v[7] = (short)f2bf(v1[3]);
      }
      *(short8*)&As[row * 40 + acg * 8] = v;
    }
    {
      const unsigned short* bp = Bt + (size_t)(bn * 128 + bnr) * K + k0 + bhf * 16;
      *(short8*)&Bs[bnr * 40 + bhf * 16] = *(const short8*)bp;
      *(short8*)&Bs[bnr * 40 + bhf * 16 + 8] = *(const short8*)(bp + 8);
    }
    __syncthreads();
    short8 af[4], bf[4];
#pragma unroll
    for (int m = 0; m < 4; ++m) af[m] = *(const short8*)&As[(wm * 64 + m * 16 + lo) * 40 + hi * 8];
#pragma unroll
    for (int n = 0; n < 4; ++n) bf[n] = *(const short8*)&Bs[(wn * 64 + n * 16 + lo) * 40 + hi * 8];
#pragma unroll
    for (int m = 0; m < 4; ++m)
#pragma unroll
      for (int n = 0; n < 4; ++n) acc[m][n] = mfma16(af[m], bf[n], acc[m][n]);
  }

#pragma unroll
  for (int m = 0; m < 4; ++m)
#pragma unroll
    for (int n = 0; n < 4; ++n) {
      int col = bn * 128 + wn * 64 + n * 16 + lo;
#pragma unroll
      for (int j = 0; j < 4; ++j) {
        int row = row0 + wm * 64 + m * 16 + hi * 4 + j;
        if (row < M) {
          unsigned short v = f2bf(acc[m][n][j]);
          if (z) {
            int bb = row / 77, tt = row - bb * 77;
            VbfT[(size_t)col * 656 + bb * 80 + tt] = v;
          } else {
            Kbf[(size_t)row * N + col] = v;
          }
        }
      }
    }
}

// ---------------------------------------------------------------------------
// Fused launch: blocks 0..99 = K/V projections (run FIRST so they overlap the
// first gemm wave instead of extending the tail); 100..2659 = Q-GEMM.
// ---------------------------------------------------------------------------
__launch_bounds__(256, 2)
__global__ void gemm_qkv(const unsigned short* __restrict__ Xbf,
                         const unsigned short* __restrict__ WqT,
                         unsigned short* __restrict__ Qbf,
                         const float* __restrict__ enc,
                         const unsigned short* __restrict__ WkT,
                         const unsigned short* __restrict__ WvT,
                         unsigned short* __restrict__ Kbf,
                         unsigned short* __restrict__ VbfT) {
  __shared__ alignas(128) unsigned short sh[4 * 8192];
  int bid = blockIdx.x;
  if (bid < 100) {
    int z = bid / 50, r = bid - z * 50;
    int bm = r / 10, bn = r - bm * 10;
    kv_body(sh, enc, z ? WvT : WkT, Kbf, VbfT, bn, bm, z);
  } else {
    int b2 = bid - 100;
    int nid = (b2 & 7) * 320 + (b2 >> 3);   // bijective XCD swizzle over 2560
    gemm128_body<false, false>(sh, Xbf, WqT, Qbf, nullptr, 32768, 1280, 1280, nid);
  }
}

// ---------------------------------------------------------------------------
// Attention: Sk=77 single tile.  Q/K from global; V from global V^T [1280][656].
// ---------------------------------------------------------------------------
#define QB 64
__launch_bounds__(256)
__global__ void attn_kernel(const unsigned short* __restrict__ Q,
                            const unsigned short* __restrict__ Kp,
                            const unsigned short* __restrict__ VpT,
                            unsigned short* __restrict__ O) {
  __shared__ alignas(16) unsigned short Ps[QB][104];
  int tile = blockIdx.x, bh = blockIdx.y;
  int b = bh >> 3, h = bh & 7;
  int tid = threadIdx.x;

  for (int cid = tid; cid < QB * 16; cid += 256) {
    int r = cid / 16, c = 80 + (cid & 15);
    Ps[r][c] = 0;
  }

  int l = tid & 63, wid = tid >> 6, lo = l & 15, hi = l >> 4;

  const unsigned short* qrow =
      Q + (size_t)(b * 4096 + tile * QB + wid * 16 + lo) * 1280 + h * 160;
  short8 a[5];
#pragma unroll
  for (int kt = 0; kt < 5; ++kt) a[kt] = *(const short8*)&qrow[kt * 32 + hi * 8];

  const unsigned short* Kb = Kp + (size_t)(b * 77) * 1280 + h * 160;
  f32x4 z = {0.0f, 0.0f, 0.0f, 0.0f};
  f32x4 sc[5];
#pragma unroll
  for (int n = 0; n < 5; ++n) sc[n] = z;
#pragma unroll
  for (int n = 0; n < 5; ++n) {
    const unsigned short* krow = Kb + (size_t)(n * 16 + lo) * 1280;
#pragma unroll
    for (int kt = 0; kt < 5; ++kt) {
      short8 bb = *(const short8*)&krow[kt * 32 + hi * 8];
      sc[n] = mfma16(a[kt], bb, sc[n]);
    }
  }
  if (lo >= 13) { sc[4][0] = -1e30f; sc[4][1] = -1e30f; sc[4][2] = -1e30f; sc[4][3] = -1e30f; }

  float pinv[4];
#pragma unroll
  for (int j = 0; j < 4; ++j) {
    float mx = sc[0][j];
#pragma unroll
    for (int n = 1; n < 5; ++n) mx = fmaxf(mx, sc[n][j]);
#pragma unroll
    for (int msk = 1; msk < 16; msk <<= 1) mx = fmaxf(mx, __shfl_xor(mx, msk, 64));
    float s = 0.0f;
#pragma unroll
    for (int n = 0; n < 5; ++n) {
      float p = __expf(sc[n][j] - mx);
      sc[n][j] = p;
      s += p;
    }
#pragma unroll
    for (int msk = 1; msk < 16; msk <<= 1) s += __shfl_xor(s, msk, 64);
    pinv[j] = 1.0f / s;
  }
#pragma unroll
  for (int n = 0; n < 5; ++n)
#pragma unroll
    for (int j = 0; j < 4; ++j)
      Ps[wid * 16 + hi * 4 + j][n * 16 + lo] = f2bf(sc[n][j] * pinv[j]);
  __syncthreads();

  f32x4 o[10];
#pragma unroll
  for (int n = 0; n < 10; ++n) o[n] = z;
#pragma unroll
  for (int kt = 0; kt < 3; ++kt) {
    short8 pa = *(const short8*)&Ps[wid * 16 + lo][kt * 32 + hi * 8];
#pragma unroll
    for (int n = 0; n < 10; ++n) {
      const unsigned short* vrow = VpT + (size_t)(h * 160 + n * 16 + lo) * 656 + b * 80;
      short8 vb = *(const short8*)&vrow[kt * 32 + hi * 8];
      o[n] = mfma16(pa, vb, o[n]);
    }
  }
  unsigned short* Ob = O + (size_t)(b * 4096 + tile * QB + wid * 16 + hi * 4) * 1280 + h * 160;
#pragma unroll
  for (int n = 0; n < 10; ++n)
#pragma unroll
    for (int j = 0; j < 4; ++j)
      Ob[(size_t)j * 1280 + n * 16 + lo] = f2bf(o[n][j]);
}

// ---------------------------------------------------------------------------
extern "C" void kernel_launch(void* const* d_in, const int* in_sizes, int n_in,
                              void* d_out, int out_size, void* d_ws, size_t ws_size,
                              hipStream_t stream) {
  const float* hidden   = (const float*)d_in[0];
  const float* enc      = (const float*)d_in[1];
  const float* Pq_in    = (const float*)d_in[2];
  const float* Pk_in    = (const float*)d_in[3];
  const float* Pv_in    = (const float*)d_in[4];
  const float* Pout_in  = (const float*)d_in[5];
  const float* Pq_out   = (const float*)d_in[6];
  const float* Pk_out   = (const float*)d_in[7];
  const float* Pv_out   = (const float*)d_in[8];
  const float* Pout_out = (const float*)d_in[9];
  const float* Wq       = (const float*)d_in[10];
  const float* Wk       = (const float*)d_in[11];
  const float* Wv       = (const float*)d_in[12];
  const float* Wout     = (const float*)d_in[13];
  const float* bout     = (const float*)d_in[14];
  const float* q_scale  = (const float*)d_in[15];
  const float* k_scale  = (const float*)d_in[16];
  const float* v_scale  = (const float*)d_in[17];
  const float* out_scale= (const float*)d_in[18];

  char* w = (char*)d_ws;
  unsigned short* attnO = (unsigned short*)w; w += 32768LL * 1280 * 2;
  unsigned short* WqT   = (unsigned short*)w; w += 1280LL * 1280 * 2;
  unsigned short* WkT   = (unsigned short*)w; w += 1280LL * 768 * 2;
  unsigned short* WvT   = (unsigned short*)w; w += 1280LL * 768 * 2;
  unsigned short* WoT   = (unsigned short*)w; w += 1280LL * 1280 * 2;
  unsigned short* Kbf   = (unsigned short*)w; w += 616LL * 1280 * 2;
  unsigned short* VbfT  = (unsigned short*)w; w += 1280LL * 656 * 2;
  float* cQq_in   = (float*)w; w += 16LL * 80 * 80 * 4;
  float* cQout_in = (float*)w; w += 16LL * 80 * 80 * 4;
  float* cQq_out  = (float*)w; w += 16LL * 80 * 80 * 4;
  float* cQk_out  = (float*)w; w += 16LL * 80 * 80 * 4;
  float* cQv_out  = (float*)w; w += 16LL * 80 * 80 * 4;
  float* cQout_out= (float*)w; w += 16LL * 80 * 80 * 4;
  float* cQk_in   = (float*)w; w += 16LL * 48 * 48 * 4;
  float* cQv_in   = (float*)w; w += 16LL * 48 * 48 * 4;

  unsigned short* Xbf = (unsigned short*)d_out;
  unsigned short* Qbf = Xbf + 32768LL * 1280;

  CayleyPtrs cp;
  cp.P[0] = Pq_in;    cp.Q[0] = cQq_in;
  cp.P[1] = Pout_in;  cp.Q[1] = cQout_in;
  cp.P[2] = Pq_out;   cp.Q[2] = cQq_out;
  cp.P[3] = Pk_out;   cp.Q[3] = cQk_out;
  cp.P[4] = Pv_out;   cp.Q[4] = cQv_out;
  cp.P[5] = Pout_out; cp.Q[5] = cQout_out;
  cp.P[6] = Pk_in;    cp.Q[6] = cQk_in;
  cp.P[7] = Pv_in;    cp.Q[7] = cQv_in;

  // 1. front: cayley (128) + f32->bf16 convert (1920) + VbfT zero (16)
  front_kernel<<<2064, 256, 0, stream>>>(cp, hidden, Xbf, VbfT);

  // 2. effective weights
  const float ATTN_SCALE = 0.07905694150420949f;  // 160^-0.5
  BuildArgs ba;
  ba.Qin[0] = cQq_in;   ba.W[0] = Wq;   ba.Qout[0] = cQq_out;   ba.scale[0] = q_scale;
  ba.WeffT[0] = WqT;    ba.extra[0] = ATTN_SCALE; ba.b[0] = 80; ba.Kin[0] = 1280;
  ba.Qin[1] = cQk_in;   ba.W[1] = Wk;   ba.Qout[1] = cQk_out;   ba.scale[1] = k_scale;
  ba.WeffT[1] = WkT;    ba.extra[1] = 1.0f;       ba.b[1] = 48; ba.Kin[1] = 768;
  ba.Qin[2] = cQv_in;   ba.W[2] = Wv;   ba.Qout[2] = cQv_out;   ba.scale[2] = v_scale;
  ba.WeffT[2] = WvT;    ba.extra[2] = 1.0f;       ba.b[2] = 48; ba.Kin[2] = 768;
  ba.Qin[3] = cQout_in; ba.W[3] = Wout; ba.Qout[3] = cQout_out; ba.scale[3] = out_scale;
  ba.WeffT[3] = WoT;    ba.extra[3] = 1.0f;       ba.b[3] = 80; ba.Kin[3] = 1280;
  build_all<<<dim3(16, 16, 4), 256, 0, stream>>>(ba);

  // 3. K/V projections (first) + Q projection in one launch
  gemm_qkv<<<2660, 256, 0, stream>>>(Xbf, WqT, Qbf, enc, WkT, WvT, Kbf, VbfT);
  // 4. attention
  attn_kernel<<<dim3(64, 64), 256, 0, stream>>>(Qbf, Kbf, VbfT, attnO);
  // 5. output projection + bias
  gemm128<true, true><<<2560, 256, 0, stream>>>(attnO, WoT, d_out, bout, 32768, 1280, 1280);
}